// Round 1
// baseline (2791.961 us; speedup 1.0000x reference)
//
#include <hip/hip_runtime.h>
#include <hip/hip_bf16.h>

#define SCALE_F 0.125f

__device__ __forceinline__ float bf_lo(unsigned int u){ return __uint_as_float(u << 16); }
__device__ __forceinline__ float bf_hi(unsigned int u){ return __uint_as_float(u & 0xffff0000u); }

// GEMM modes:
// 0: plain f32 out [M,512]
// 1: dual-A (K=1024: rows 0..511 from A, 512..1023 from A2), plain f32 out
// 2: Q-layout  f32 out [b,h,q,64]   (M=2048),  scaled
// 3: S-layout  f32 out [b,h,n,64]   (M=128)
// 4: W-layout bf16 out [b,h,n,t,64] (M=32768)
template<int MODE>
__global__ __launch_bounds__(256)
void gemm_k(const float* __restrict__ A, const float* __restrict__ A2,
            const float* __restrict__ W, const float* __restrict__ bias,
            float* __restrict__ outf, __hip_bfloat16* __restrict__ outb,
            float scale, int M, int K)
{
  __shared__ float As[16][132];   // A^T tile: [k][m], padded
  __shared__ float Bs[16][132];   // [k][n], padded
  const int m0 = blockIdx.x * 128;
  const int n0 = blockIdx.y * 128;
  const int tid = threadIdx.x;
  const int ty = tid >> 4, tx = tid & 15;

  float acc[8][8];
  #pragma unroll
  for (int i = 0; i < 8; i++)
    #pragma unroll
    for (int j = 0; j < 8; j++) acc[i][j] = 0.f;

  for (int k0 = 0; k0 < K; k0 += 16) {
    const float* Asrc = A;
    int kk = k0;
    if (MODE == 1) { if (k0 >= 512) { Asrc = A2; kk = k0 - 512; } }
    // A tile: 128 rows x 16 k  (512 float4 loads)
    #pragma unroll
    for (int i = 0; i < 2; i++) {
      int f4 = tid + i * 256;
      int r = f4 >> 2, c4 = f4 & 3;
      float4 v = *(const float4*)&Asrc[(size_t)(m0 + r) * 512 + kk + c4 * 4];
      As[c4 * 4 + 0][r] = v.x;
      As[c4 * 4 + 1][r] = v.y;
      As[c4 * 4 + 2][r] = v.z;
      As[c4 * 4 + 3][r] = v.w;
    }
    // B tile: 16 k x 128 cols
    #pragma unroll
    for (int i = 0; i < 2; i++) {
      int f4 = tid + i * 256;
      int r = f4 >> 5, c4 = f4 & 31;
      *(float4*)&Bs[r][c4 * 4] = *(const float4*)&W[(size_t)(k0 + r) * 512 + n0 + c4 * 4];
    }
    __syncthreads();
    #pragma unroll
    for (int kk2 = 0; kk2 < 16; kk2++) {
      float a[8], b[8];
      #pragma unroll
      for (int i = 0; i < 8; i++) a[i] = As[kk2][ty * 8 + i];
      #pragma unroll
      for (int j = 0; j < 8; j++) b[j] = Bs[kk2][tx + j * 16];
      #pragma unroll
      for (int i = 0; i < 8; i++)
        #pragma unroll
        for (int j = 0; j < 8; j++) acc[i][j] += a[i] * b[j];
    }
    __syncthreads();
  }

  #pragma unroll
  for (int i = 0; i < 8; i++) {
    int m = m0 + ty * 8 + i;
    #pragma unroll
    for (int j = 0; j < 8; j++) {
      int c = n0 + tx + j * 16;
      float v = (acc[i][j] + bias[c]) * scale;
      if (MODE == 0 || MODE == 1) {
        outf[(size_t)m * 512 + c] = v;
      } else if (MODE == 2) {
        int bb = m >> 9, qq = m & 511, hh = c >> 6, d = c & 63;
        outf[((((size_t)bb * 8 + hh) * 512 + qq) << 6) + d] = v;
      } else if (MODE == 3) {
        int bb = m >> 5, nn = m & 31, hh = c >> 6, d = c & 63;
        outf[((((size_t)bb * 8 + hh) * 32 + nn) << 6) + d] = v;
      } else {
        int bb = m >> 13, r = m & 8191, nn = r >> 8, tt = r & 255, hh = c >> 6, d = c & 63;
        outb[(((((size_t)bb * 8 + hh) * 32 + nn) * 256 + tt) << 6) + d] = __float2bfloat16(v);
      }
    }
  }
}

// Sentence-level attention: scores over nb=32, softmax, ctx_s; also emits attn_s.
__global__ __launch_bounds__(256)
void sent_attn(const float* __restrict__ qs,   // [b,h,512,64]  (pre-scaled)
               const float* __restrict__ ks,   // [b,h,32,64]
               const float* __restrict__ vs,   // [b,h,32,64]
               float* __restrict__ attn_s,     // [b,h,512,32]
               float* __restrict__ ctx_s)      // [b,512,512]
{
  __shared__ float qsS[32][68];
  __shared__ float ksS[32][68];
  __shared__ float vsS[32][68];
  __shared__ float sS[32][36];
  const int bh = blockIdx.y, b = bh >> 3, h = bh & 7;
  const int q0 = blockIdx.x * 32;
  const int tid = threadIdx.x;

  #pragma unroll
  for (int i = 0; i < 2; i++) {
    int idx = tid + i * 256;          // float4 units (512 per tile)
    int r = idx >> 4, c = (idx & 15) * 4;
    *(float4*)&qsS[r][c] = *(const float4*)&qs[((size_t)bh * 512 + q0 + r) * 64 + c];
    *(float4*)&ksS[r][c] = *(const float4*)&ks[((size_t)bh * 32 + r) * 64 + c];
    *(float4*)&vsS[r][c] = *(const float4*)&vs[((size_t)bh * 32 + r) * 64 + c];
  }
  __syncthreads();

  #pragma unroll
  for (int it = 0; it < 4; it++) {
    int pair = tid + it * 256;
    int qq = pair >> 5, nn = pair & 31;
    float s = 0.f;
    #pragma unroll
    for (int k = 0; k < 64; k++) s += qsS[qq][k] * ksS[nn][k];
    sS[qq][nn] = s;
  }
  __syncthreads();

  if (tid < 32) {
    int qq = tid;
    float m = -1e30f;
    #pragma unroll
    for (int n = 0; n < 32; n++) m = fmaxf(m, sS[qq][n]);
    float p[32];
    float sum = 0.f;
    #pragma unroll
    for (int n = 0; n < 32; n++) { p[n] = __expf(sS[qq][n] - m); sum += p[n]; }
    float inv = 1.f / sum;
    #pragma unroll
    for (int n = 0; n < 32; n++) {
      float pv = p[n] * inv;
      sS[qq][n] = pv;
      attn_s[((size_t)bh * 512 + q0 + qq) * 32 + n] = pv;
    }
  }
  __syncthreads();

  #pragma unroll
  for (int it = 0; it < 8; it++) {
    int idx = tid + it * 256;
    int qq = idx >> 6, d = idx & 63;
    float c = 0.f;
    #pragma unroll
    for (int n = 0; n < 32; n++) c += sS[qq][n] * vsS[n][d];
    ctx_s[((size_t)b * 512 + q0 + qq) * 512 + h * 64 + d] = c;
  }
}

// Token-level attention, fused per-block softmax + sentence weighting.
// Grid: (8 q-tiles, 32 bh). Thread = (q = tid>>2, quarter = tid&3).
__global__ __launch_bounds__(256, 1)
void tok_attn(const float* __restrict__ qw,            // [b,h,512,64] (pre-scaled)
              const __hip_bfloat16* __restrict__ kw,   // [b,h,32,256,64]
              const __hip_bfloat16* __restrict__ vw,   // [b,h,32,256,64]
              const float* __restrict__ attn_s,        // [b,h,512,32]
              float* __restrict__ ctx_w)               // [b,512,512]
{
  __shared__ unsigned short bufK[256][72];  // 72-ushort rows: conflict-free b128
  __shared__ unsigned short bufV[256][72];
  const int bh = blockIdx.y;
  const int b = bh >> 3, h = bh & 7;
  const int q0 = blockIdx.x * 64;
  const int tid = threadIdx.x;
  const int q = tid >> 2;
  const int quarter = tid & 3;

  const float* qrow = qw + ((size_t)bh * 512 + q0 + q) * 64;
  float qreg[64];
  #pragma unroll
  for (int i = 0; i < 16; i++) {
    float4 v = *(const float4*)&qrow[i * 4];
    qreg[i * 4 + 0] = v.x; qreg[i * 4 + 1] = v.y;
    qreg[i * 4 + 2] = v.z; qreg[i * 4 + 3] = v.w;
  }
  float acc[64];
  #pragma unroll
  for (int d = 0; d < 64; d++) acc[d] = 0.f;

  const unsigned short* kwb = (const unsigned short*)(kw + (size_t)bh * 32 * 256 * 64);
  const unsigned short* vwb = (const unsigned short*)(vw + (size_t)bh * 32 * 256 * 64);
  const float* asrow = attn_s + ((size_t)bh * 512 + q0 + q) * 32;

  for (int n = 0; n < 32; n++) {
    __syncthreads();
    #pragma unroll
    for (int i = 0; i < 8; i++) {
      int idx = tid + i * 256;          // uint4 units (2048 per tile)
      int r = idx >> 3, c = (idx & 7) * 8;
      *(uint4*)&bufK[r][c] = *(const uint4*)&kwb[((size_t)n * 256 + r) * 64 + c];
      *(uint4*)&bufV[r][c] = *(const uint4*)&vwb[((size_t)n * 256 + r) * 64 + c];
    }
    __syncthreads();

    float part[64];
    #pragma unroll
    for (int d = 0; d < 64; d++) part[d] = 0.f;
    float lsum = 0.f;

    for (int j = 0; j < 64; j++) {
      int t = (j << 2) | quarter;
      float sj = 0.f;
      #pragma unroll
      for (int kc = 0; kc < 8; kc++) {
        uint4 raw = *(const uint4*)&bufK[t][kc * 8];
        sj += qreg[kc * 8 + 0] * bf_lo(raw.x) + qreg[kc * 8 + 1] * bf_hi(raw.x)
            + qreg[kc * 8 + 2] * bf_lo(raw.y) + qreg[kc * 8 + 3] * bf_hi(raw.y)
            + qreg[kc * 8 + 4] * bf_lo(raw.z) + qreg[kc * 8 + 5] * bf_hi(raw.z)
            + qreg[kc * 8 + 6] * bf_lo(raw.w) + qreg[kc * 8 + 7] * bf_hi(raw.w);
      }
      float e = __expf(sj);            // softmax shift-invariant; |s| < ~1.5
      lsum += e;
      #pragma unroll
      for (int dc = 0; dc < 8; dc++) {
        uint4 raw = *(const uint4*)&bufV[t][dc * 8];
        part[dc * 8 + 0] += e * bf_lo(raw.x); part[dc * 8 + 1] += e * bf_hi(raw.x);
        part[dc * 8 + 2] += e * bf_lo(raw.y); part[dc * 8 + 3] += e * bf_hi(raw.y);
        part[dc * 8 + 4] += e * bf_lo(raw.z); part[dc * 8 + 5] += e * bf_hi(raw.z);
        part[dc * 8 + 6] += e * bf_lo(raw.w); part[dc * 8 + 7] += e * bf_hi(raw.w);
      }
    }
    lsum += __shfl_xor(lsum, 1);
    lsum += __shfl_xor(lsum, 2);
    float coef = asrow[n] / lsum;
    #pragma unroll
    for (int d = 0; d < 64; d++) acc[d] += coef * part[d];
  }

  #pragma unroll
  for (int d = 0; d < 64; d++) {
    acc[d] += __shfl_xor(acc[d], 1);
    acc[d] += __shfl_xor(acc[d], 2);
  }
  if (quarter == 0) {
    float* dst = ctx_w + ((size_t)b * 512 + q0 + q) * 512 + h * 64;
    #pragma unroll
    for (int i = 0; i < 16; i++) {
      float4 v;
      v.x = acc[i * 4 + 0]; v.y = acc[i * 4 + 1];
      v.z = acc[i * 4 + 2]; v.w = acc[i * 4 + 3];
      *(float4*)&dst[i * 4] = v;
    }
  }
}

extern "C" void kernel_launch(void* const* d_in, const int* in_sizes, int n_in,
                              void* d_out, int out_size, void* d_ws, size_t ws_size,
                              hipStream_t stream)
{
  (void)in_sizes; (void)n_in; (void)out_size; (void)ws_size;
  const float* q    = (const float*)d_in[0];
  const float* k_w  = (const float*)d_in[1];
  const float* v_w  = (const float*)d_in[2];
  const float* k_s  = (const float*)d_in[3];
  const float* v_s  = (const float*)d_in[4];
  const float* W_qs = (const float*)d_in[5];  const float* b_qs = (const float*)d_in[6];
  const float* W_ks = (const float*)d_in[7];  const float* b_ks = (const float*)d_in[8];
  const float* W_vs = (const float*)d_in[9];  const float* b_vs = (const float*)d_in[10];
  const float* W_qw = (const float*)d_in[11]; const float* b_qw = (const float*)d_in[12];
  const float* W_kw = (const float*)d_in[13]; const float* b_kw = (const float*)d_in[14];
  const float* W_vw = (const float*)d_in[15]; const float* b_vw = (const float*)d_in[16];
  const float* W_fc1= (const float*)d_in[17]; const float* b_fc1= (const float*)d_in[18];
  const float* W_fc = (const float*)d_in[19]; const float* b_fc = (const float*)d_in[20];
  float* out = (float*)d_out;

  char* ws = (char*)d_ws;
  const size_t MB = 1ull << 20;
  float* qs_ws    = (float*)(ws + 0 * MB);    // [b,h,512,64]  4 MB (pre-scaled)
  float* qw_ws    = (float*)(ws + 4 * MB);    // [b,h,512,64]  4 MB (pre-scaled)
  float* ks_ws    = (float*)(ws + 8 * MB);    // [b,h,32,64]   256 KB
  float* vs_ws    = (float*)(ws + 9 * MB);    // [b,h,32,64]   256 KB
  float* attns_ws = (float*)(ws + 10 * MB);   // [b,h,512,32]  2 MB
  float* ctxs_ws  = (float*)(ws + 12 * MB);   // [b,512,512]   4 MB
  float* ctxsf_ws = (float*)(ws + 16 * MB);   // [b,512,512]   4 MB
  float* ctxw_ws  = (float*)(ws + 20 * MB);   // [b,512,512]   4 MB
  __hip_bfloat16* kw_ws = (__hip_bfloat16*)(ws + 24 * MB);  // [b,h,32,256,64] 32 MB
  __hip_bfloat16* vw_ws = (__hip_bfloat16*)(ws + 56 * MB);  // [b,h,32,256,64] 32 MB

  dim3 blk(256);
  // projections
  gemm_k<2><<<dim3(16, 4), blk, 0, stream>>>(q,   nullptr, W_qs, b_qs, qs_ws, nullptr, SCALE_F, 2048, 512);
  gemm_k<2><<<dim3(16, 4), blk, 0, stream>>>(q,   nullptr, W_qw, b_qw, qw_ws, nullptr, SCALE_F, 2048, 512);
  gemm_k<3><<<dim3(1, 4),  blk, 0, stream>>>(k_s, nullptr, W_ks, b_ks, ks_ws, nullptr, 1.f, 128, 512);
  gemm_k<3><<<dim3(1, 4),  blk, 0, stream>>>(v_s, nullptr, W_vs, b_vs, vs_ws, nullptr, 1.f, 128, 512);
  gemm_k<4><<<dim3(256, 4),blk, 0, stream>>>(k_w, nullptr, W_kw, b_kw, nullptr, kw_ws, 1.f, 32768, 512);
  gemm_k<4><<<dim3(256, 4),blk, 0, stream>>>(v_w, nullptr, W_vw, b_vw, nullptr, vw_ws, 1.f, 32768, 512);
  // sentence attention (+ attn_s for token level)
  sent_attn<<<dim3(16, 32), blk, 0, stream>>>(qs_ws, ks_ws, vs_ws, attns_ws, ctxs_ws);
  gemm_k<0><<<dim3(16, 4), blk, 0, stream>>>(ctxs_ws, nullptr, W_fc1, b_fc1, ctxsf_ws, nullptr, 1.f, 2048, 512);
  // token attention
  tok_attn<<<dim3(8, 32), blk, 0, stream>>>(qw_ws, kw_ws, vw_ws, attns_ws, ctxw_ws);
  // final combine: concat([ctx_s_fc, ctx_w]) @ W_fc + b_fc
  gemm_k<1><<<dim3(16, 4), blk, 0, stream>>>(ctxsf_ws, ctxw_ws, W_fc, b_fc, out, nullptr, 1.f, 2048, 1024);
}

// Round 3
// 1327.889 us; speedup vs baseline: 2.1026x; 2.1026x over previous
//
#include <hip/hip_runtime.h>
#include <hip/hip_bf16.h>

#define SCALE_F 0.125f

typedef __attribute__((ext_vector_type(8))) short short8;
typedef __attribute__((ext_vector_type(4))) float f32x4;

__device__ __forceinline__ unsigned short f2b(float f){
  unsigned int x = __float_as_uint(f);
  return (unsigned short)((x + 0x7fffu + ((x >> 16) & 1u)) >> 16);
}

// GEMM modes:
// 0: plain f32 out [M,512]
// 1: dual-A (K=1024: rows 0..511 from A, 512..1023 from A2), plain f32 out
// 2: Q-layout  f32 out [b,h,q,64]   (M=2048),  scaled
// 3: S-layout  f32 out [b,h,n,64]   (M=128)
// 4: W-layout bf16 out [b,h,n,t,64] (M=32768)
template<int MODE>
__global__ __launch_bounds__(256)
void gemm_k(const float* __restrict__ A, const float* __restrict__ A2,
            const float* __restrict__ W, const float* __restrict__ bias,
            float* __restrict__ outf, __hip_bfloat16* __restrict__ outb,
            float scale, int M, int K)
{
  __shared__ float As[16][132];   // A^T tile: [k][m], padded
  __shared__ float Bs[16][132];   // [k][n], padded
  const int m0 = blockIdx.x * 128;
  const int n0 = blockIdx.y * 128;
  const int tid = threadIdx.x;
  const int ty = tid >> 4, tx = tid & 15;

  float acc[8][8];
  #pragma unroll
  for (int i = 0; i < 8; i++)
    #pragma unroll
    for (int j = 0; j < 8; j++) acc[i][j] = 0.f;

  for (int k0 = 0; k0 < K; k0 += 16) {
    const float* Asrc = A;
    int kk = k0;
    if (MODE == 1) { if (k0 >= 512) { Asrc = A2; kk = k0 - 512; } }
    #pragma unroll
    for (int i = 0; i < 2; i++) {
      int f4 = tid + i * 256;
      int r = f4 >> 2, c4 = f4 & 3;
      float4 v = *(const float4*)&Asrc[(size_t)(m0 + r) * 512 + kk + c4 * 4];
      As[c4 * 4 + 0][r] = v.x;
      As[c4 * 4 + 1][r] = v.y;
      As[c4 * 4 + 2][r] = v.z;
      As[c4 * 4 + 3][r] = v.w;
    }
    #pragma unroll
    for (int i = 0; i < 2; i++) {
      int f4 = tid + i * 256;
      int r = f4 >> 5, c4 = f4 & 31;
      *(float4*)&Bs[r][c4 * 4] = *(const float4*)&W[(size_t)(k0 + r) * 512 + n0 + c4 * 4];
    }
    __syncthreads();
    #pragma unroll
    for (int kk2 = 0; kk2 < 16; kk2++) {
      float a[8], b[8];
      #pragma unroll
      for (int i = 0; i < 8; i++) a[i] = As[kk2][ty * 8 + i];
      #pragma unroll
      for (int j = 0; j < 8; j++) b[j] = Bs[kk2][tx + j * 16];
      #pragma unroll
      for (int i = 0; i < 8; i++)
        #pragma unroll
        for (int j = 0; j < 8; j++) acc[i][j] += a[i] * b[j];
    }
    __syncthreads();
  }

  #pragma unroll
  for (int i = 0; i < 8; i++) {
    int m = m0 + ty * 8 + i;
    #pragma unroll
    for (int j = 0; j < 8; j++) {
      int c = n0 + tx + j * 16;
      float v = (acc[i][j] + bias[c]) * scale;
      if (MODE == 0 || MODE == 1) {
        outf[(size_t)m * 512 + c] = v;
      } else if (MODE == 2) {
        int bb = m >> 9, qq = m & 511, hh = c >> 6, d = c & 63;
        outf[((((size_t)bb * 8 + hh) * 512 + qq) << 6) + d] = v;
      } else if (MODE == 3) {
        int bb = m >> 5, nn = m & 31, hh = c >> 6, d = c & 63;
        outf[((((size_t)bb * 8 + hh) * 32 + nn) << 6) + d] = v;
      } else {
        int bb = m >> 13, r = m & 8191, nn = r >> 8, tt = r & 255, hh = c >> 6, d = c & 63;
        outb[(((((size_t)bb * 8 + hh) * 32 + nn) * 256 + tt) << 6) + d] = __float2bfloat16(v);
      }
    }
  }
}

// Sentence-level attention: scores over nb=32, softmax, ctx_s; also emits attn_s.
__global__ __launch_bounds__(256)
void sent_attn(const float* __restrict__ qs,   // [b,h,512,64]  (pre-scaled)
               const float* __restrict__ ks,   // [b,h,32,64]
               const float* __restrict__ vs,   // [b,h,32,64]
               float* __restrict__ attn_s,     // [b,h,512,32]
               float* __restrict__ ctx_s)      // [b,512,512]
{
  __shared__ float qsS[32][68];
  __shared__ float ksS[32][68];
  __shared__ float vsS[32][68];
  __shared__ float sS[32][36];
  const int bh = blockIdx.y, b = bh >> 3, h = bh & 7;
  const int q0 = blockIdx.x * 32;
  const int tid = threadIdx.x;

  #pragma unroll
  for (int i = 0; i < 2; i++) {
    int idx = tid + i * 256;
    int r = idx >> 4, c = (idx & 15) * 4;
    *(float4*)&qsS[r][c] = *(const float4*)&qs[((size_t)bh * 512 + q0 + r) * 64 + c];
    *(float4*)&ksS[r][c] = *(const float4*)&ks[((size_t)bh * 32 + r) * 64 + c];
    *(float4*)&vsS[r][c] = *(const float4*)&vs[((size_t)bh * 32 + r) * 64 + c];
  }
  __syncthreads();

  #pragma unroll
  for (int it = 0; it < 4; it++) {
    int pair = tid + it * 256;
    int qq = pair >> 5, nn = pair & 31;
    float s = 0.f;
    #pragma unroll
    for (int k = 0; k < 64; k++) s += qsS[qq][k] * ksS[nn][k];
    sS[qq][nn] = s;
  }
  __syncthreads();

  if (tid < 32) {
    int qq = tid;
    float m = -1e30f;
    #pragma unroll
    for (int n = 0; n < 32; n++) m = fmaxf(m, sS[qq][n]);
    float p[32];
    float sum = 0.f;
    #pragma unroll
    for (int n = 0; n < 32; n++) { p[n] = __expf(sS[qq][n] - m); sum += p[n]; }
    float inv = 1.f / sum;
    #pragma unroll
    for (int n = 0; n < 32; n++) {
      float pv = p[n] * inv;
      sS[qq][n] = pv;
      attn_s[((size_t)bh * 512 + q0 + qq) * 32 + n] = pv;
    }
  }
  __syncthreads();

  #pragma unroll
  for (int it = 0; it < 8; it++) {
    int idx = tid + it * 256;
    int qq = idx >> 6, d = idx & 63;
    float c = 0.f;
    #pragma unroll
    for (int n = 0; n < 32; n++) c += sS[qq][n] * vsS[n][d];
    ctx_s[((size_t)b * 512 + q0 + qq) * 512 + h * 64 + d] = c;
  }
}

// MFMA token-level attention.
// Grid (8 q-tiles, 32 bh, 2 n-chunks), 256 threads = 4 waves x 16 q-rows.
__global__ __launch_bounds__(256, 2)
void tok_attn_mfma(const float* __restrict__ qw,            // [b,h,512,64] f32 pre-scaled
                   const __hip_bfloat16* __restrict__ kw,   // [b,h,32,256,64]
                   const __hip_bfloat16* __restrict__ vw,   // [b,h,32,256,64]
                   const float* __restrict__ attn_s,        // [b,h,512,32]
                   float* __restrict__ part0,
                   float* __restrict__ part1)
{
  __shared__ unsigned short kvbuf[18432];    // K as [256][72]  OR  Vt as [64][264]
  __shared__ unsigned short pbuf[64 * 264];  // P as [64 q-rows][256 t + 8 pad]
  const int bh = blockIdx.y, b = bh >> 3, h = bh & 7;
  const int tid = threadIdx.x;
  const int wv = tid >> 6, lane = tid & 63, lg = lane >> 4, lr = lane & 15;
  const int qbase = blockIdx.x * 64 + wv * 16;
  const int n0 = blockIdx.z * 16;

  // Q B-fragments: lane -> Q[qbase+lr][ks*32 + lg*8 + j], bf16. Hoisted for all n.
  short8 qfrag[2];
  {
    const float* qrow = qw + ((size_t)bh * 512 + qbase + lr) * 64;
    #pragma unroll
    for (int ks = 0; ks < 2; ks++) {
      float4 u0 = *(const float4*)&qrow[ks * 32 + lg * 8];
      float4 u1 = *(const float4*)&qrow[ks * 32 + lg * 8 + 4];
      short8 t;
      t[0] = f2b(u0.x); t[1] = f2b(u0.y); t[2] = f2b(u0.z); t[3] = f2b(u0.w);
      t[4] = f2b(u1.x); t[5] = f2b(u1.y); t[6] = f2b(u1.z); t[7] = f2b(u1.w);
      qfrag[ks] = t;
    }
  }
  // attn_s[q, n0..n0+16) for this lane's q-row
  float asv[16];
  {
    const float* ap = attn_s + ((size_t)bh * 512 + qbase + lr) * 32 + n0;
    #pragma unroll
    for (int i = 0; i < 4; i++) {
      float4 u = *(const float4*)&ap[i * 4];
      asv[i * 4 + 0] = u.x; asv[i * 4 + 1] = u.y;
      asv[i * 4 + 2] = u.z; asv[i * 4 + 3] = u.w;
    }
  }

  f32x4 acc[4];
  #pragma unroll
  for (int dt = 0; dt < 4; dt++) acc[dt] = (f32x4){0.f, 0.f, 0.f, 0.f};

  const unsigned short* kwb = (const unsigned short*)(kw + (size_t)bh * 32 * 256 * 64);
  const unsigned short* vwb = (const unsigned short*)(vw + (size_t)bh * 32 * 256 * 64);
  const unsigned int pbase = (wv * 16 + lr) * 264;

  for (int ni = 0; ni < 16; ni++) {
    const int n = n0 + ni;
    __syncthreads();   // prior PV done reading kvbuf
    {  // stage K: one row per thread -> conflict-free padded LDS writes
      const unsigned short* src = kwb + ((size_t)n * 256 + tid) * 64;
      uint4 r[8];
      #pragma unroll
      for (int j = 0; j < 8; j++) r[j] = *(const uint4*)&src[j * 8];
      #pragma unroll
      for (int j = 0; j < 8; j++) *(uint4*)&kvbuf[tid * 72 + j * 8] = r[j];
    }
    __syncthreads();

    // Sᵀ tile: C[t, q] = K·Qᵀ ; 16 t-tiles x 2 k-steps
    f32x4 sfr[16];
    #pragma unroll
    for (int tt = 0; tt < 16; tt++) sfr[tt] = (f32x4){0.f, 0.f, 0.f, 0.f};
    #pragma unroll
    for (int tt = 0; tt < 16; tt++) {
      #pragma unroll
      for (int ks = 0; ks < 2; ks++) {
        short8 kf = *(const short8*)&kvbuf[(16 * tt + lr) * 72 + ks * 32 + lg * 8];
        sfr[tt] = __builtin_amdgcn_mfma_f32_16x16x32_bf16(kf, qfrag[ks], sfr[tt], 0, 0, 0);
      }
    }
    // softmax (shift-free: |s| small) + sentence weighting, all for q = qbase+lr
    float lsum = 0.f;
    #pragma unroll
    for (int tt = 0; tt < 16; tt++) {
      #pragma unroll
      for (int i = 0; i < 4; i++) {
        float e = __expf(sfr[tt][i]);
        sfr[tt][i] = e;
        lsum += e;
      }
    }
    lsum += __shfl_xor(lsum, 16);
    lsum += __shfl_xor(lsum, 32);
    const float coef = asv[ni] / lsum;
    #pragma unroll
    for (int tt = 0; tt < 16; tt++) {
      uint2 pk;
      pk.x = (unsigned)f2b(sfr[tt][0] * coef) | ((unsigned)f2b(sfr[tt][1] * coef) << 16);
      pk.y = (unsigned)f2b(sfr[tt][2] * coef) | ((unsigned)f2b(sfr[tt][3] * coef) << 16);
      *(uint2*)&pbuf[pbase + tt * 16 + lg * 4] = pk;   // P[q][t], 4 contiguous t
    }
    __syncthreads();   // all QK reads of kvbuf done
    {  // stage V transposed: Vt[d][t], one V-row per thread
      const unsigned short* src = vwb + ((size_t)n * 256 + tid) * 64;
      uint4 r[8];
      #pragma unroll
      for (int j = 0; j < 8; j++) r[j] = *(const uint4*)&src[j * 8];
      const unsigned short* rs = (const unsigned short*)r;
      #pragma unroll
      for (int d = 0; d < 64; d++) kvbuf[d * 264 + tid] = rs[d];
    }
    __syncthreads();

    // PV: acc[q, d] += P[q, t] * V[t, d], 8 k-steps over t
    #pragma unroll
    for (int ks = 0; ks < 8; ks++) {
      short8 pa = *(const short8*)&pbuf[pbase + ks * 32 + lg * 8];
      #pragma unroll
      for (int dt = 0; dt < 4; dt++) {
        short8 vb = *(const short8*)&kvbuf[(16 * dt + lr) * 264 + ks * 32 + lg * 8];
        acc[dt] = __builtin_amdgcn_mfma_f32_16x16x32_bf16(pa, vb, acc[dt], 0, 0, 0);
      }
    }
  }

  float* pout = blockIdx.z ? part1 : part0;
  #pragma unroll
  for (int dt = 0; dt < 4; dt++) {
    #pragma unroll
    for (int i = 0; i < 4; i++) {
      int qg = blockIdx.x * 64 + wv * 16 + lg * 4 + i;
      pout[((size_t)b * 512 + qg) * 512 + h * 64 + dt * 16 + lr] = acc[dt][i];
    }
  }
}

__global__ __launch_bounds__(256)
void reduce_add2(const float4* __restrict__ a, const float4* __restrict__ b,
                 float4* __restrict__ o)
{
  int i = blockIdx.x * 256 + threadIdx.x;
  float4 x = a[i], y = b[i];
  x.x += y.x; x.y += y.y; x.z += y.z; x.w += y.w;
  o[i] = x;
}

extern "C" void kernel_launch(void* const* d_in, const int* in_sizes, int n_in,
                              void* d_out, int out_size, void* d_ws, size_t ws_size,
                              hipStream_t stream)
{
  (void)in_sizes; (void)n_in; (void)out_size; (void)ws_size;
  const float* q    = (const float*)d_in[0];
  const float* k_w  = (const float*)d_in[1];
  const float* v_w  = (const float*)d_in[2];
  const float* k_s  = (const float*)d_in[3];
  const float* v_s  = (const float*)d_in[4];
  const float* W_qs = (const float*)d_in[5];  const float* b_qs = (const float*)d_in[6];
  const float* W_ks = (const float*)d_in[7];  const float* b_ks = (const float*)d_in[8];
  const float* W_vs = (const float*)d_in[9];  const float* b_vs = (const float*)d_in[10];
  const float* W_qw = (const float*)d_in[11]; const float* b_qw = (const float*)d_in[12];
  const float* W_kw = (const float*)d_in[13]; const float* b_kw = (const float*)d_in[14];
  const float* W_vw = (const float*)d_in[15]; const float* b_vw = (const float*)d_in[16];
  const float* W_fc1= (const float*)d_in[17]; const float* b_fc1= (const float*)d_in[18];
  const float* W_fc = (const float*)d_in[19]; const float* b_fc = (const float*)d_in[20];
  float* out = (float*)d_out;

  char* ws = (char*)d_ws;
  const size_t MB = 1ull << 20;
  float* qs_ws    = (float*)(ws + 0 * MB);    // [b,h,512,64]  4 MB (dead after sent_attn)
  float* qw_ws    = (float*)(ws + 4 * MB);    // [b,h,512,64]  4 MB (pre-scaled)
  float* ks_ws    = (float*)(ws + 8 * MB);    // [b,h,32,64]
  float* vs_ws    = (float*)(ws + 9 * MB);    // [b,h,32,64]
  float* attns_ws = (float*)(ws + 10 * MB);   // [b,h,512,32]  2 MB
  float* ctxs_ws  = (float*)(ws + 12 * MB);   // [b,512,512]   4 MB (dead after fc1 gemm)
  float* ctxsf_ws = (float*)(ws + 16 * MB);   // [b,512,512]   4 MB
  float* ctxw_ws  = (float*)(ws + 20 * MB);   // [b,512,512]   4 MB
  __hip_bfloat16* kw_ws = (__hip_bfloat16*)(ws + 24 * MB);  // [b,h,32,256,64] 32 MB
  __hip_bfloat16* vw_ws = (__hip_bfloat16*)(ws + 56 * MB);  // [b,h,32,256,64] 32 MB
  // tok_attn partials reuse dead regions (both fully overwritten every call):
  float* part0 = (float*)(ws + 0 * MB);       // over qs_ws   (4 MB)
  float* part1 = (float*)(ws + 12 * MB);      // over ctxs_ws (4 MB)

  dim3 blk(256);
  // projections
  gemm_k<2><<<dim3(16, 4), blk, 0, stream>>>(q,   nullptr, W_qs, b_qs, qs_ws, nullptr, SCALE_F, 2048, 512);
  gemm_k<2><<<dim3(16, 4), blk, 0, stream>>>(q,   nullptr, W_qw, b_qw, qw_ws, nullptr, SCALE_F, 2048, 512);
  gemm_k<3><<<dim3(1, 4),  blk, 0, stream>>>(k_s, nullptr, W_ks, b_ks, ks_ws, nullptr, 1.f, 128, 512);
  gemm_k<3><<<dim3(1, 4),  blk, 0, stream>>>(v_s, nullptr, W_vs, b_vs, vs_ws, nullptr, 1.f, 128, 512);
  gemm_k<4><<<dim3(256, 4),blk, 0, stream>>>(k_w, nullptr, W_kw, b_kw, nullptr, kw_ws, 1.f, 32768, 512);
  gemm_k<4><<<dim3(256, 4),blk, 0, stream>>>(v_w, nullptr, W_vw, b_vw, nullptr, vw_ws, 1.f, 32768, 512);
  // sentence attention (+ attn_s for token level); consumes qs_ws/ks_ws/vs_ws
  sent_attn<<<dim3(16, 32), blk, 0, stream>>>(qs_ws, ks_ws, vs_ws, attns_ws, ctxs_ws);
  gemm_k<0><<<dim3(16, 4), blk, 0, stream>>>(ctxs_ws, nullptr, W_fc1, b_fc1, ctxsf_ws, nullptr, 1.f, 2048, 512);
  // token attention (MFMA) -> partials -> reduce
  tok_attn_mfma<<<dim3(8, 32, 2), blk, 0, stream>>>(qw_ws, kw_ws, vw_ws, attns_ws, part0, part1);
  reduce_add2<<<dim3(1024), blk, 0, stream>>>((const float4*)part0, (const float4*)part1, (float4*)ctxw_ws);
  // final combine: concat([ctx_s_fc1, ctx_w]) @ W_fc + b_fc
  gemm_k<1><<<dim3(16, 4), blk, 0, stream>>>(ctxsf_ws, ctxw_ws, W_fc, b_fc, out, nullptr, 1.f, 2048, 1024);
}

// Round 4
// 1037.832 us; speedup vs baseline: 2.6902x; 1.2795x over previous
//
#include <hip/hip_runtime.h>
#include <hip/hip_bf16.h>

#define SCALE_F 0.125f

typedef __attribute__((ext_vector_type(8))) short short8;
typedef __attribute__((ext_vector_type(4))) float f32x4;

__device__ __forceinline__ unsigned short f2b(float f){
  unsigned int x = __float_as_uint(f);
  return (unsigned short)((x + 0x7fffu + ((x >> 16) & 1u)) >> 16);
}

// GEMM modes (vector-ALU path, small Ms):
// 0: plain f32 out [M,512]
// 1: dual-A (K=1024: rows 0..511 from A, 512..1023 from A2), plain f32 out
// 2: Q-layout  f32 out [b,h,q,64]   (M=2048),  scaled
// 3: S-layout  f32 out [b,h,n,64]   (M=128)
template<int MODE>
__global__ __launch_bounds__(256)
void gemm_k(const float* __restrict__ A, const float* __restrict__ A2,
            const float* __restrict__ W, const float* __restrict__ bias,
            float* __restrict__ outf, __hip_bfloat16* __restrict__ outb,
            float scale, int M, int K)
{
  __shared__ float As[16][132];   // A^T tile: [k][m], padded
  __shared__ float Bs[16][132];   // [k][n], padded
  const int m0 = blockIdx.x * 128;
  const int n0 = blockIdx.y * 128;
  const int tid = threadIdx.x;
  const int ty = tid >> 4, tx = tid & 15;

  float acc[8][8];
  #pragma unroll
  for (int i = 0; i < 8; i++)
    #pragma unroll
    for (int j = 0; j < 8; j++) acc[i][j] = 0.f;

  for (int k0 = 0; k0 < K; k0 += 16) {
    const float* Asrc = A;
    int kk = k0;
    if (MODE == 1) { if (k0 >= 512) { Asrc = A2; kk = k0 - 512; } }
    #pragma unroll
    for (int i = 0; i < 2; i++) {
      int f4 = tid + i * 256;
      int r = f4 >> 2, c4 = f4 & 3;
      float4 v = *(const float4*)&Asrc[(size_t)(m0 + r) * 512 + kk + c4 * 4];
      As[c4 * 4 + 0][r] = v.x;
      As[c4 * 4 + 1][r] = v.y;
      As[c4 * 4 + 2][r] = v.z;
      As[c4 * 4 + 3][r] = v.w;
    }
    #pragma unroll
    for (int i = 0; i < 2; i++) {
      int f4 = tid + i * 256;
      int r = f4 >> 5, c4 = f4 & 31;
      *(float4*)&Bs[r][c4 * 4] = *(const float4*)&W[(size_t)(k0 + r) * 512 + n0 + c4 * 4];
    }
    __syncthreads();
    #pragma unroll
    for (int kk2 = 0; kk2 < 16; kk2++) {
      float a[8], b[8];
      #pragma unroll
      for (int i = 0; i < 8; i++) a[i] = As[kk2][ty * 8 + i];
      #pragma unroll
      for (int j = 0; j < 8; j++) b[j] = Bs[kk2][tx + j * 16];
      #pragma unroll
      for (int i = 0; i < 8; i++)
        #pragma unroll
        for (int j = 0; j < 8; j++) acc[i][j] += a[i] * b[j];
    }
    __syncthreads();
  }

  #pragma unroll
  for (int i = 0; i < 8; i++) {
    int m = m0 + ty * 8 + i;
    #pragma unroll
    for (int j = 0; j < 8; j++) {
      int c = n0 + tx + j * 16;
      float v = (acc[i][j] + bias[c]) * scale;
      if (MODE == 0 || MODE == 1) {
        outf[(size_t)m * 512 + c] = v;
      } else if (MODE == 2) {
        int bb = m >> 9, qq = m & 511, hh = c >> 6, d = c & 63;
        outf[((((size_t)bb * 8 + hh) * 512 + qq) << 6) + d] = v;
      } else if (MODE == 3) {
        int bb = m >> 5, nn = m & 31, hh = c >> 6, d = c & 63;
        outf[((((size_t)bb * 8 + hh) * 32 + nn) << 6) + d] = v;
      }
    }
  }
}

// Transpose-cast W [512k,512n] f32 -> WT [n][k] bf16 (z picks which W).
__global__ __launch_bounds__(256)
void wcast_t(const float* __restrict__ W0, unsigned short* __restrict__ T0,
             const float* __restrict__ W1, unsigned short* __restrict__ T1)
{
  __shared__ unsigned short tile[64][72];
  const float* W = blockIdx.z ? W1 : W0;
  unsigned short* T = blockIdx.z ? T1 : T0;
  int k0 = blockIdx.x * 64, n0 = blockIdx.y * 64;
  #pragma unroll
  for (int j = 0; j < 16; j++) {
    int idx = threadIdx.x + j * 256;
    int r = idx >> 6, c = idx & 63;
    tile[r][c] = f2b(W[(size_t)(k0 + r) * 512 + n0 + c]);
  }
  __syncthreads();
  #pragma unroll
  for (int j = 0; j < 16; j++) {
    int idx = threadIdx.x + j * 256;
    int r = idx >> 6, c = idx & 63;
    T[(size_t)(n0 + r) * 512 + k0 + c] = tile[c][r];
  }
}

// MFMA projection GEMM: out[m,n] = A[m,:]·W[:,n] + bias[n], written in
// W-layout bf16 [b,h,nb,nt,64].  A is f32 (cast to bf16 in staging),
// BT is pre-transposed bf16 [n][k].  Tile 128x128, BK=64, 4 waves x 64x64.
// LDS rows are 128 B -> XOR-swizzle ((row&7)<<3 ushorts) on write+read.
__global__ __launch_bounds__(256)
void proj_gemm(const float* __restrict__ A,          // [32768,512] f32
               const unsigned short* __restrict__ BT,// [512n][512k] bf16
               const float* __restrict__ bias,       // [512]
               __hip_bfloat16* __restrict__ outW)    // [b,h,32,256,64]
{
  __shared__ unsigned short As[128 * 64];
  __shared__ unsigned short Bs[128 * 64];
  const int m0 = blockIdx.x * 128, n0 = blockIdx.y * 128;
  const int tid = threadIdx.x;
  const int lane = tid & 63, wv = tid >> 6, lr = lane & 15, lg = lane >> 4;
  const int wr = wv >> 1, wc = wv & 1;

  f32x4 acc[4][4];
  #pragma unroll
  for (int mi = 0; mi < 4; mi++)
    #pragma unroll
    for (int nj = 0; nj < 4; nj++) acc[mi][nj] = (f32x4){0.f, 0.f, 0.f, 0.f};

  for (int k0 = 0; k0 < 512; k0 += 64) {
    // issue all global loads first (overlap with barrier wait)
    float4 a0[4], a1[4]; uint4 bq[4];
    #pragma unroll
    for (int j = 0; j < 4; j++) {
      int idx = tid + j * 256;
      int row = idx >> 3, c8 = idx & 7;
      const float* ap = A + (size_t)(m0 + row) * 512 + k0 + c8 * 8;
      a0[j] = *(const float4*)ap;
      a1[j] = *(const float4*)(ap + 4);
      bq[j] = *(const uint4*)(BT + (size_t)(n0 + row) * 512 + k0 + c8 * 8);
    }
    __syncthreads();   // prior K-step's LDS reads complete
    #pragma unroll
    for (int j = 0; j < 4; j++) {
      int idx = tid + j * 256;
      int row = idx >> 3, c8 = idx & 7;
      int off = row * 64 + ((c8 * 8) ^ ((row & 7) << 3));
      short8 pk;
      pk[0] = (short)f2b(a0[j].x); pk[1] = (short)f2b(a0[j].y);
      pk[2] = (short)f2b(a0[j].z); pk[3] = (short)f2b(a0[j].w);
      pk[4] = (short)f2b(a1[j].x); pk[5] = (short)f2b(a1[j].y);
      pk[6] = (short)f2b(a1[j].z); pk[7] = (short)f2b(a1[j].w);
      *(short8*)&As[off] = pk;
      *(uint4*)&Bs[off] = bq[j];
    }
    __syncthreads();
    #pragma unroll
    for (int ks = 0; ks < 2; ks++) {
      short8 af[4], bfp[4];
      #pragma unroll
      for (int mi = 0; mi < 4; mi++) {
        int row = wr * 64 + mi * 16 + lr;
        af[mi] = *(const short8*)&As[row * 64 + ((ks * 32 + lg * 8) ^ ((row & 7) << 3))];
      }
      #pragma unroll
      for (int nj = 0; nj < 4; nj++) {
        int row = wc * 64 + nj * 16 + lr;
        bfp[nj] = *(const short8*)&Bs[row * 64 + ((ks * 32 + lg * 8) ^ ((row & 7) << 3))];
      }
      #pragma unroll
      for (int mi = 0; mi < 4; mi++)
        #pragma unroll
        for (int nj = 0; nj < 4; nj++)
          acc[mi][nj] = __builtin_amdgcn_mfma_f32_16x16x32_bf16(af[mi], bfp[nj], acc[mi][nj], 0, 0, 0);
    }
  }

  // epilogue: C[m = ..+lg*4+i][n = ..+lr], bias add, W-layout bf16 store
  #pragma unroll
  for (int nj = 0; nj < 4; nj++) {
    int n = n0 + wc * 64 + nj * 16 + lr;
    float bv = bias[n];
    int hh = n >> 6, d = n & 63;
    #pragma unroll
    for (int mi = 0; mi < 4; mi++) {
      #pragma unroll
      for (int i = 0; i < 4; i++) {
        int m = m0 + wr * 64 + mi * 16 + lg * 4 + i;
        int bb = m >> 13, r = m & 8191, nn = r >> 8, tt = r & 255;
        outW[(((((size_t)bb * 8 + hh) * 32 + nn) * 256 + tt) << 6) + d] =
            __float2bfloat16(acc[mi][nj][i] + bv);
      }
    }
  }
}

// Sentence-level attention: scores over nb=32, softmax, ctx_s; also emits attn_s.
__global__ __launch_bounds__(256)
void sent_attn(const float* __restrict__ qs,   // [b,h,512,64]  (pre-scaled)
               const float* __restrict__ ks,   // [b,h,32,64]
               const float* __restrict__ vs,   // [b,h,32,64]
               float* __restrict__ attn_s,     // [b,h,512,32]
               float* __restrict__ ctx_s)      // [b,512,512]
{
  __shared__ float qsS[32][68];
  __shared__ float ksS[32][68];
  __shared__ float vsS[32][68];
  __shared__ float sS[32][36];
  const int bh = blockIdx.y, b = bh >> 3, h = bh & 7;
  const int q0 = blockIdx.x * 32;
  const int tid = threadIdx.x;

  #pragma unroll
  for (int i = 0; i < 2; i++) {
    int idx = tid + i * 256;
    int r = idx >> 4, c = (idx & 15) * 4;
    *(float4*)&qsS[r][c] = *(const float4*)&qs[((size_t)bh * 512 + q0 + r) * 64 + c];
    *(float4*)&ksS[r][c] = *(const float4*)&ks[((size_t)bh * 32 + r) * 64 + c];
    *(float4*)&vsS[r][c] = *(const float4*)&vs[((size_t)bh * 32 + r) * 64 + c];
  }
  __syncthreads();

  #pragma unroll
  for (int it = 0; it < 4; it++) {
    int pair = tid + it * 256;
    int qq = pair >> 5, nn = pair & 31;
    float s = 0.f;
    #pragma unroll
    for (int k = 0; k < 64; k++) s += qsS[qq][k] * ksS[nn][k];
    sS[qq][nn] = s;
  }
  __syncthreads();

  if (tid < 32) {
    int qq = tid;
    float m = -1e30f;
    #pragma unroll
    for (int n = 0; n < 32; n++) m = fmaxf(m, sS[qq][n]);
    float p[32];
    float sum = 0.f;
    #pragma unroll
    for (int n = 0; n < 32; n++) { p[n] = __expf(sS[qq][n] - m); sum += p[n]; }
    float inv = 1.f / sum;
    #pragma unroll
    for (int n = 0; n < 32; n++) {
      float pv = p[n] * inv;
      sS[qq][n] = pv;
      attn_s[((size_t)bh * 512 + q0 + qq) * 32 + n] = pv;
    }
  }
  __syncthreads();

  #pragma unroll
  for (int it = 0; it < 8; it++) {
    int idx = tid + it * 256;
    int qq = idx >> 6, d = idx & 63;
    float c = 0.f;
    #pragma unroll
    for (int n = 0; n < 32; n++) c += sS[qq][n] * vsS[n][d];
    ctx_s[((size_t)b * 512 + q0 + qq) * 512 + h * 64 + d] = c;
  }
}

// MFMA token-level attention.
// Grid (8 q-tiles, 32 bh, 2 n-chunks), 256 threads = 4 waves x 16 q-rows.
__global__ __launch_bounds__(256, 2)
void tok_attn_mfma(const float* __restrict__ qw,            // [b,h,512,64] f32 pre-scaled
                   const __hip_bfloat16* __restrict__ kw,   // [b,h,32,256,64]
                   const __hip_bfloat16* __restrict__ vw,   // [b,h,32,256,64]
                   const float* __restrict__ attn_s,        // [b,h,512,32]
                   float* __restrict__ part0,
                   float* __restrict__ part1)
{
  __shared__ unsigned short kvbuf[18432];    // K as [256][72]  OR  Vt as [64][264]
  __shared__ unsigned short pbuf[64 * 264];  // P as [64 q-rows][256 t + 8 pad]
  const int bh = blockIdx.y, b = bh >> 3, h = bh & 7;
  const int tid = threadIdx.x;
  const int wv = tid >> 6, lane = tid & 63, lg = lane >> 4, lr = lane & 15;
  const int qbase = blockIdx.x * 64 + wv * 16;
  const int n0 = blockIdx.z * 16;

  short8 qfrag[2];
  {
    const float* qrow = qw + ((size_t)bh * 512 + qbase + lr) * 64;
    #pragma unroll
    for (int ks = 0; ks < 2; ks++) {
      float4 u0 = *(const float4*)&qrow[ks * 32 + lg * 8];
      float4 u1 = *(const float4*)&qrow[ks * 32 + lg * 8 + 4];
      short8 t;
      t[0] = f2b(u0.x); t[1] = f2b(u0.y); t[2] = f2b(u0.z); t[3] = f2b(u0.w);
      t[4] = f2b(u1.x); t[5] = f2b(u1.y); t[6] = f2b(u1.z); t[7] = f2b(u1.w);
      qfrag[ks] = t;
    }
  }
  float asv[16];
  {
    const float* ap = attn_s + ((size_t)bh * 512 + qbase + lr) * 32 + n0;
    #pragma unroll
    for (int i = 0; i < 4; i++) {
      float4 u = *(const float4*)&ap[i * 4];
      asv[i * 4 + 0] = u.x; asv[i * 4 + 1] = u.y;
      asv[i * 4 + 2] = u.z; asv[i * 4 + 3] = u.w;
    }
  }

  f32x4 acc[4];
  #pragma unroll
  for (int dt = 0; dt < 4; dt++) acc[dt] = (f32x4){0.f, 0.f, 0.f, 0.f};

  const unsigned short* kwb = (const unsigned short*)(kw + (size_t)bh * 32 * 256 * 64);
  const unsigned short* vwb = (const unsigned short*)(vw + (size_t)bh * 32 * 256 * 64);
  const unsigned int pbase = (wv * 16 + lr) * 264;

  for (int ni = 0; ni < 16; ni++) {
    const int n = n0 + ni;
    __syncthreads();
    {
      const unsigned short* src = kwb + ((size_t)n * 256 + tid) * 64;
      uint4 r[8];
      #pragma unroll
      for (int j = 0; j < 8; j++) r[j] = *(const uint4*)&src[j * 8];
      #pragma unroll
      for (int j = 0; j < 8; j++) *(uint4*)&kvbuf[tid * 72 + j * 8] = r[j];
    }
    __syncthreads();

    f32x4 sfr[16];
    #pragma unroll
    for (int tt = 0; tt < 16; tt++) sfr[tt] = (f32x4){0.f, 0.f, 0.f, 0.f};
    #pragma unroll
    for (int tt = 0; tt < 16; tt++) {
      #pragma unroll
      for (int ks = 0; ks < 2; ks++) {
        short8 kf = *(const short8*)&kvbuf[(16 * tt + lr) * 72 + ks * 32 + lg * 8];
        sfr[tt] = __builtin_amdgcn_mfma_f32_16x16x32_bf16(kf, qfrag[ks], sfr[tt], 0, 0, 0);
      }
    }
    float lsum = 0.f;
    #pragma unroll
    for (int tt = 0; tt < 16; tt++) {
      #pragma unroll
      for (int i = 0; i < 4; i++) {
        float e = __expf(sfr[tt][i]);
        sfr[tt][i] = e;
        lsum += e;
      }
    }
    lsum += __shfl_xor(lsum, 16);
    lsum += __shfl_xor(lsum, 32);
    const float coef = asv[ni] / lsum;
    #pragma unroll
    for (int tt = 0; tt < 16; tt++) {
      uint2 pk;
      pk.x = (unsigned)f2b(sfr[tt][0] * coef) | ((unsigned)f2b(sfr[tt][1] * coef) << 16);
      pk.y = (unsigned)f2b(sfr[tt][2] * coef) | ((unsigned)f2b(sfr[tt][3] * coef) << 16);
      *(uint2*)&pbuf[pbase + tt * 16 + lg * 4] = pk;
    }
    __syncthreads();
    {
      const unsigned short* src = vwb + ((size_t)n * 256 + tid) * 64;
      uint4 r[8];
      #pragma unroll
      for (int j = 0; j < 8; j++) r[j] = *(const uint4*)&src[j * 8];
      const unsigned short* rs = (const unsigned short*)r;
      #pragma unroll
      for (int d = 0; d < 64; d++) kvbuf[d * 264 + tid] = rs[d];
    }
    __syncthreads();

    #pragma unroll
    for (int ks = 0; ks < 8; ks++) {
      short8 pa = *(const short8*)&pbuf[pbase + ks * 32 + lg * 8];
      #pragma unroll
      for (int dt = 0; dt < 4; dt++) {
        short8 vb = *(const short8*)&kvbuf[(16 * dt + lr) * 264 + ks * 32 + lg * 8];
        acc[dt] = __builtin_amdgcn_mfma_f32_16x16x32_bf16(pa, vb, acc[dt], 0, 0, 0);
      }
    }
  }

  float* pout = blockIdx.z ? part1 : part0;
  #pragma unroll
  for (int dt = 0; dt < 4; dt++) {
    #pragma unroll
    for (int i = 0; i < 4; i++) {
      int qg = blockIdx.x * 64 + wv * 16 + lg * 4 + i;
      pout[((size_t)b * 512 + qg) * 512 + h * 64 + dt * 16 + lr] = acc[dt][i];
    }
  }
}

__global__ __launch_bounds__(256)
void reduce_add2(const float4* __restrict__ a, const float4* __restrict__ b,
                 float4* __restrict__ o)
{
  int i = blockIdx.x * 256 + threadIdx.x;
  float4 x = a[i], y = b[i];
  x.x += y.x; x.y += y.y; x.z += y.z; x.w += y.w;
  o[i] = x;
}

extern "C" void kernel_launch(void* const* d_in, const int* in_sizes, int n_in,
                              void* d_out, int out_size, void* d_ws, size_t ws_size,
                              hipStream_t stream)
{
  (void)in_sizes; (void)n_in; (void)out_size; (void)ws_size;
  const float* q    = (const float*)d_in[0];
  const float* k_w  = (const float*)d_in[1];
  const float* v_w  = (const float*)d_in[2];
  const float* k_s  = (const float*)d_in[3];
  const float* v_s  = (const float*)d_in[4];
  const float* W_qs = (const float*)d_in[5];  const float* b_qs = (const float*)d_in[6];
  const float* W_ks = (const float*)d_in[7];  const float* b_ks = (const float*)d_in[8];
  const float* W_vs = (const float*)d_in[9];  const float* b_vs = (const float*)d_in[10];
  const float* W_qw = (const float*)d_in[11]; const float* b_qw = (const float*)d_in[12];
  const float* W_kw = (const float*)d_in[13]; const float* b_kw = (const float*)d_in[14];
  const float* W_vw = (const float*)d_in[15]; const float* b_vw = (const float*)d_in[16];
  const float* W_fc1= (const float*)d_in[17]; const float* b_fc1= (const float*)d_in[18];
  const float* W_fc = (const float*)d_in[19]; const float* b_fc = (const float*)d_in[20];
  float* out = (float*)d_out;

  char* ws = (char*)d_ws;
  const size_t MB = 1ull << 20;
  const size_t KB = 1ull << 10;
  float* qs_ws    = (float*)(ws + 0 * MB);       // [b,h,512,64] 4 MB (dead after sent_attn)
  float* qw_ws    = (float*)(ws + 4 * MB);       // [b,h,512,64] 4 MB
  float* ks_ws    = (float*)(ws + 8 * MB);       // [b,h,32,64] 256 KB
  unsigned short* WkT = (unsigned short*)(ws + 8 * MB + 512 * KB);  // [512n][512k] bf16, 512 KB
  float* vs_ws    = (float*)(ws + 9 * MB);       // [b,h,32,64] 256 KB
  unsigned short* WvT = (unsigned short*)(ws + 9 * MB + 512 * KB);  // 512 KB
  float* attns_ws = (float*)(ws + 10 * MB);      // [b,h,512,32] 2 MB
  float* ctxs_ws  = (float*)(ws + 12 * MB);      // [b,512,512] 4 MB (dead after fc1 gemm)
  float* ctxsf_ws = (float*)(ws + 16 * MB);      // [b,512,512] 4 MB
  float* ctxw_ws  = (float*)(ws + 20 * MB);      // [b,512,512] 4 MB
  __hip_bfloat16* kw_ws = (__hip_bfloat16*)(ws + 24 * MB);  // [b,h,32,256,64] 32 MB
  __hip_bfloat16* vw_ws = (__hip_bfloat16*)(ws + 56 * MB);  // [b,h,32,256,64] 32 MB
  float* part0 = (float*)(ws + 0 * MB);          // over qs_ws   (4 MB)
  float* part1 = (float*)(ws + 12 * MB);         // over ctxs_ws (4 MB)

  dim3 blk(256);
  // weight transpose-casts for the MFMA projections
  wcast_t<<<dim3(8, 8, 2), blk, 0, stream>>>(W_kw, WkT, W_vw, WvT);
  // small projections (vector path)
  gemm_k<2><<<dim3(16, 4), blk, 0, stream>>>(q,   nullptr, W_qs, b_qs, qs_ws, nullptr, SCALE_F, 2048, 512);
  gemm_k<2><<<dim3(16, 4), blk, 0, stream>>>(q,   nullptr, W_qw, b_qw, qw_ws, nullptr, SCALE_F, 2048, 512);
  gemm_k<3><<<dim3(1, 4),  blk, 0, stream>>>(k_s, nullptr, W_ks, b_ks, ks_ws, nullptr, 1.f, 128, 512);
  gemm_k<3><<<dim3(1, 4),  blk, 0, stream>>>(v_s, nullptr, W_vs, b_vs, vs_ws, nullptr, 1.f, 128, 512);
  // big projections (MFMA path)
  proj_gemm<<<dim3(256, 4), blk, 0, stream>>>(k_w, WkT, b_kw, kw_ws);
  proj_gemm<<<dim3(256, 4), blk, 0, stream>>>(v_w, WvT, b_vw, vw_ws);
  // sentence attention (+ attn_s for token level)
  sent_attn<<<dim3(16, 32), blk, 0, stream>>>(qs_ws, ks_ws, vs_ws, attns_ws, ctxs_ws);
  gemm_k<0><<<dim3(16, 4), blk, 0, stream>>>(ctxs_ws, nullptr, W_fc1, b_fc1, ctxsf_ws, nullptr, 1.f, 2048, 512);
  // token attention (MFMA) -> partials -> reduce
  tok_attn_mfma<<<dim3(8, 32, 2), blk, 0, stream>>>(qw_ws, kw_ws, vw_ws, attns_ws, part0, part1);
  reduce_add2<<<dim3(1024), blk, 0, stream>>>((const float4*)part0, (const float4*)part1, (float4*)ctxw_ws);
  // final combine: concat([ctx_s_fc1, ctx_w]) @ W_fc + b_fc
  gemm_k<1><<<dim3(16, 4), blk, 0, stream>>>(ctxsf_ws, ctxw_ws, W_fc, b_fc, out, nullptr, 1.f, 2048, 1024);
}

// Round 5
// 354.543 us; speedup vs baseline: 7.8748x; 2.9272x over previous
//
#include <hip/hip_runtime.h>
#include <hip/hip_bf16.h>

#define SCALE_F 0.125f

typedef __attribute__((ext_vector_type(8))) short short8;
typedef __attribute__((ext_vector_type(4))) float f32x4;

__device__ __forceinline__ unsigned short f2b(float f){
  unsigned int x = __float_as_uint(f);
  return (unsigned short)((x + 0x7fffu + ((x >> 16) & 1u)) >> 16);
}
__device__ __forceinline__ float b2f(unsigned short h){
  return __uint_as_float((unsigned int)h << 16);
}

// Transpose-cast W [512k,512n] f32 -> WT [n][k] bf16 (z picks which W).
__global__ __launch_bounds__(256)
void wcast_t(const float* __restrict__ W0, unsigned short* __restrict__ T0,
             const float* __restrict__ W1, unsigned short* __restrict__ T1)
{
  __shared__ unsigned short tile[64][72];
  const float* W = blockIdx.z ? W1 : W0;
  unsigned short* T = blockIdx.z ? T1 : T0;
  int k0 = blockIdx.x * 64, n0 = blockIdx.y * 64;
  #pragma unroll
  for (int j = 0; j < 16; j++) {
    int idx = threadIdx.x + j * 256;
    int r = idx >> 6, c = idx & 63;
    tile[r][c] = f2b(W[(size_t)(k0 + r) * 512 + n0 + c]);
  }
  __syncthreads();
  #pragma unroll
  for (int j = 0; j < 16; j++) {
    int idx = threadIdx.x + j * 256;
    int r = idx >> 6, c = idx & 63;
    T[(size_t)(n0 + r) * 512 + k0 + c] = tile[c][r];
  }
}

// Small-M MFMA GEMM with bf16x3 split (f32-class accuracy).
// out = A[M,K] @ W[K,512] + bias, 64x64 tile, BK=64, 4 waves.
// blockIdx.z selects the (A,W,bias,out) pair (fused independent GEMMs).
// MODE 0: plain f32 out [M,512]
// MODE 1: K=1024; k>=512 rows of A come from p0+p1 (summed in staging)
// MODE 2: Q-layout out [b,h,512,64], scaled
// MODE 3: S-layout out [b,h,32,64]
template<int MODE>
__global__ __launch_bounds__(256)
void sgemm_mfma(const float* __restrict__ A0, const float* __restrict__ A1,
                const float* __restrict__ p0, const float* __restrict__ p1,
                const float* __restrict__ W0, const float* __restrict__ W1,
                const float* __restrict__ bias0, const float* __restrict__ bias1,
                float* __restrict__ out0, float* __restrict__ out1,
                float scale, int M, int K)
{
  __shared__ unsigned short Ah[4096], Al[4096], Bh[4096], Bl[4096];
  const int z = blockIdx.z;
  const float* A    = z ? A1 : A0;
  const float* W    = z ? W1 : W0;
  const float* bias = z ? bias1 : bias0;
  float* outf       = z ? out1 : out0;

  const int m0 = blockIdx.x * 64, n0 = blockIdx.y * 64;
  const int tid = threadIdx.x;
  const int lane = tid & 63, wv = tid >> 6, lr = lane & 15, lg = lane >> 4;

  f32x4 acc[4];
  #pragma unroll
  for (int nf = 0; nf < 4; nf++) acc[nf] = (f32x4){0.f, 0.f, 0.f, 0.f};

  for (int k0 = 0; k0 < K; k0 += 64) {
    // ---- issue global loads (before barrier) ----
    float4 a0[2], a1[2];
    float bw[2][8];
    const bool dual = (MODE == 1) && (k0 >= 512);
    const int kk = dual ? (k0 - 512) : k0;
    #pragma unroll
    for (int j = 0; j < 2; j++) {
      int idx = tid + j * 256;
      int row = idx >> 3, c8 = idx & 7;
      size_t base = (size_t)(m0 + row) * 512 + kk + c8 * 8;
      if (dual) {
        float4 x0 = *(const float4*)&p0[base];
        float4 x1 = *(const float4*)&p0[base + 4];
        float4 y0 = *(const float4*)&p1[base];
        float4 y1 = *(const float4*)&p1[base + 4];
        a0[j] = (float4){x0.x + y0.x, x0.y + y0.y, x0.z + y0.z, x0.w + y0.w};
        a1[j] = (float4){x1.x + y1.x, x1.y + y1.y, x1.z + y1.z, x1.w + y1.w};
      } else {
        a0[j] = *(const float4*)&A[base];
        a1[j] = *(const float4*)&A[base + 4];
      }
    }
    #pragma unroll
    for (int j = 0; j < 2; j++) {
      int idx = tid + j * 256;
      int nl = idx >> 3, kseg = idx & 7;
      #pragma unroll
      for (int e = 0; e < 8; e++)
        bw[j][e] = W[(size_t)(k0 + kseg * 8 + e) * 512 + n0 + nl];
    }
    __syncthreads();   // prior K-step's LDS reads complete
    // ---- split + LDS writes ----
    #pragma unroll
    for (int j = 0; j < 2; j++) {
      int idx = tid + j * 256;
      int row = idx >> 3, c8 = idx & 7;
      int off = row * 64 + ((c8 * 8) ^ ((row & 7) << 3));
      float v[8] = {a0[j].x, a0[j].y, a0[j].z, a0[j].w,
                    a1[j].x, a1[j].y, a1[j].z, a1[j].w};
      short8 h, l;
      #pragma unroll
      for (int e = 0; e < 8; e++) {
        unsigned short hh = f2b(v[e]);
        h[e] = (short)hh;
        l[e] = (short)f2b(v[e] - b2f(hh));
      }
      *(short8*)&Ah[off] = h;
      *(short8*)&Al[off] = l;
    }
    #pragma unroll
    for (int j = 0; j < 2; j++) {
      int idx = tid + j * 256;
      int nl = idx >> 3, kseg = idx & 7;
      int off = nl * 64 + ((kseg * 8) ^ ((nl & 7) << 3));
      short8 h, l;
      #pragma unroll
      for (int e = 0; e < 8; e++) {
        unsigned short hh = f2b(bw[j][e]);
        h[e] = (short)hh;
        l[e] = (short)f2b(bw[j][e] - b2f(hh));
      }
      *(short8*)&Bh[off] = h;
      *(short8*)&Bl[off] = l;
    }
    __syncthreads();
    // ---- MFMA: acc += Ah·Bh + Ah·Bl + Al·Bh ----
    #pragma unroll
    for (int ks = 0; ks < 2; ks++) {
      int rowa = wv * 16 + lr;
      int aoff = rowa * 64 + ((ks * 32 + lg * 8) ^ ((rowa & 7) << 3));
      short8 ah = *(const short8*)&Ah[aoff];
      short8 al = *(const short8*)&Al[aoff];
      #pragma unroll
      for (int nf = 0; nf < 4; nf++) {
        int rowb = nf * 16 + lr;
        int boff = rowb * 64 + ((ks * 32 + lg * 8) ^ ((rowb & 7) << 3));
        short8 bh = *(const short8*)&Bh[boff];
        short8 bl = *(const short8*)&Bl[boff];
        acc[nf] = __builtin_amdgcn_mfma_f32_16x16x32_bf16(ah, bh, acc[nf], 0, 0, 0);
        acc[nf] = __builtin_amdgcn_mfma_f32_16x16x32_bf16(ah, bl, acc[nf], 0, 0, 0);
        acc[nf] = __builtin_amdgcn_mfma_f32_16x16x32_bf16(al, bh, acc[nf], 0, 0, 0);
      }
    }
  }

  // ---- epilogue ----
  #pragma unroll
  for (int nf = 0; nf < 4; nf++) {
    int n = n0 + nf * 16 + lr;
    float bv = bias[n];
    #pragma unroll
    for (int i = 0; i < 4; i++) {
      int m = m0 + wv * 16 + lg * 4 + i;
      float v = (acc[nf][i] + bv) * scale;
      if (MODE == 0 || MODE == 1) {
        outf[(size_t)m * 512 + n] = v;
      } else if (MODE == 2) {
        int bb = m >> 9, qq = m & 511, hh = n >> 6, d = n & 63;
        outf[((((size_t)bb * 8 + hh) * 512 + qq) << 6) + d] = v;
      } else {
        int bb = m >> 5, nn = m & 31, hh = n >> 6, d = n & 63;
        outf[((((size_t)bb * 8 + hh) * 32 + nn) << 6) + d] = v;
      }
    }
  }
}

// MFMA projection GEMM: out[m,n] = A[m,:]·W[:,n] + bias[n], written in
// W-layout bf16 [b,h,nb,nt,64].  Tile 128x128, BK=64, 4 waves x 64x64.
__global__ __launch_bounds__(256)
void proj_gemm(const float* __restrict__ A,          // [32768,512] f32
               const unsigned short* __restrict__ BT,// [512n][512k] bf16
               const float* __restrict__ bias,       // [512]
               __hip_bfloat16* __restrict__ outW)    // [b,h,32,256,64]
{
  __shared__ unsigned short As[128 * 64];
  __shared__ unsigned short Bs[128 * 64];
  const int m0 = blockIdx.x * 128, n0 = blockIdx.y * 128;
  const int tid = threadIdx.x;
  const int lane = tid & 63, wv = tid >> 6, lr = lane & 15, lg = lane >> 4;
  const int wr = wv >> 1, wc = wv & 1;

  f32x4 acc[4][4];
  #pragma unroll
  for (int mi = 0; mi < 4; mi++)
    #pragma unroll
    for (int nj = 0; nj < 4; nj++) acc[mi][nj] = (f32x4){0.f, 0.f, 0.f, 0.f};

  for (int k0 = 0; k0 < 512; k0 += 64) {
    float4 a0[4], a1[4]; uint4 bq[4];
    #pragma unroll
    for (int j = 0; j < 4; j++) {
      int idx = tid + j * 256;
      int row = idx >> 3, c8 = idx & 7;
      const float* ap = A + (size_t)(m0 + row) * 512 + k0 + c8 * 8;
      a0[j] = *(const float4*)ap;
      a1[j] = *(const float4*)(ap + 4);
      bq[j] = *(const uint4*)(BT + (size_t)(n0 + row) * 512 + k0 + c8 * 8);
    }
    __syncthreads();
    #pragma unroll
    for (int j = 0; j < 4; j++) {
      int idx = tid + j * 256;
      int row = idx >> 3, c8 = idx & 7;
      int off = row * 64 + ((c8 * 8) ^ ((row & 7) << 3));
      short8 pk;
      pk[0] = (short)f2b(a0[j].x); pk[1] = (short)f2b(a0[j].y);
      pk[2] = (short)f2b(a0[j].z); pk[3] = (short)f2b(a0[j].w);
      pk[4] = (short)f2b(a1[j].x); pk[5] = (short)f2b(a1[j].y);
      pk[6] = (short)f2b(a1[j].z); pk[7] = (short)f2b(a1[j].w);
      *(short8*)&As[off] = pk;
      *(uint4*)&Bs[off] = bq[j];
    }
    __syncthreads();
    #pragma unroll
    for (int ks = 0; ks < 2; ks++) {
      short8 af[4], bfp[4];
      #pragma unroll
      for (int mi = 0; mi < 4; mi++) {
        int row = wr * 64 + mi * 16 + lr;
        af[mi] = *(const short8*)&As[row * 64 + ((ks * 32 + lg * 8) ^ ((row & 7) << 3))];
      }
      #pragma unroll
      for (int nj = 0; nj < 4; nj++) {
        int row = wc * 64 + nj * 16 + lr;
        bfp[nj] = *(const short8*)&Bs[row * 64 + ((ks * 32 + lg * 8) ^ ((row & 7) << 3))];
      }
      #pragma unroll
      for (int mi = 0; mi < 4; mi++)
        #pragma unroll
        for (int nj = 0; nj < 4; nj++)
          acc[mi][nj] = __builtin_amdgcn_mfma_f32_16x16x32_bf16(af[mi], bfp[nj], acc[mi][nj], 0, 0, 0);
    }
  }

  #pragma unroll
  for (int nj = 0; nj < 4; nj++) {
    int n = n0 + wc * 64 + nj * 16 + lr;
    float bv = bias[n];
    int hh = n >> 6, d = n & 63;
    #pragma unroll
    for (int mi = 0; mi < 4; mi++) {
      #pragma unroll
      for (int i = 0; i < 4; i++) {
        int m = m0 + wr * 64 + mi * 16 + lg * 4 + i;
        int bb = m >> 13, r = m & 8191, nn = r >> 8, tt = r & 255;
        outW[(((((size_t)bb * 8 + hh) * 32 + nn) * 256 + tt) << 6) + d] =
            __float2bfloat16(acc[mi][nj][i] + bv);
      }
    }
  }
}

// Sentence-level attention: scores over nb=32, softmax, ctx_s; also emits attn_s.
__global__ __launch_bounds__(256)
void sent_attn(const float* __restrict__ qs,   // [b,h,512,64]  (pre-scaled)
               const float* __restrict__ ks,   // [b,h,32,64]
               const float* __restrict__ vs,   // [b,h,32,64]
               float* __restrict__ attn_s,     // [b,h,512,32]
               float* __restrict__ ctx_s)      // [b,512,512]
{
  __shared__ float qsS[32][68];
  __shared__ float ksS[32][68];
  __shared__ float vsS[32][68];
  __shared__ float sS[32][36];
  const int bh = blockIdx.y, b = bh >> 3, h = bh & 7;
  const int q0 = blockIdx.x * 32;
  const int tid = threadIdx.x;

  #pragma unroll
  for (int i = 0; i < 2; i++) {
    int idx = tid + i * 256;
    int r = idx >> 4, c = (idx & 15) * 4;
    *(float4*)&qsS[r][c] = *(const float4*)&qs[((size_t)bh * 512 + q0 + r) * 64 + c];
    *(float4*)&ksS[r][c] = *(const float4*)&ks[((size_t)bh * 32 + r) * 64 + c];
    *(float4*)&vsS[r][c] = *(const float4*)&vs[((size_t)bh * 32 + r) * 64 + c];
  }
  __syncthreads();

  #pragma unroll
  for (int it = 0; it < 4; it++) {
    int pair = tid + it * 256;
    int qq = pair >> 5, nn = pair & 31;
    float s = 0.f;
    #pragma unroll
    for (int k = 0; k < 64; k++) s += qsS[qq][k] * ksS[nn][k];
    sS[qq][nn] = s;
  }
  __syncthreads();

  if (tid < 32) {
    int qq = tid;
    float m = -1e30f;
    #pragma unroll
    for (int n = 0; n < 32; n++) m = fmaxf(m, sS[qq][n]);
    float p[32];
    float sum = 0.f;
    #pragma unroll
    for (int n = 0; n < 32; n++) { p[n] = __expf(sS[qq][n] - m); sum += p[n]; }
    float inv = 1.f / sum;
    #pragma unroll
    for (int n = 0; n < 32; n++) {
      float pv = p[n] * inv;
      sS[qq][n] = pv;
      attn_s[((size_t)bh * 512 + q0 + qq) * 32 + n] = pv;
    }
  }
  __syncthreads();

  #pragma unroll
  for (int it = 0; it < 8; it++) {
    int idx = tid + it * 256;
    int qq = idx >> 6, d = idx & 63;
    float c = 0.f;
    #pragma unroll
    for (int n = 0; n < 32; n++) c += sS[qq][n] * vsS[n][d];
    ctx_s[((size_t)b * 512 + q0 + qq) * 512 + h * 64 + d] = c;
  }
}

// MFMA token-level attention.
// Grid (8 q-tiles, 32 bh, 2 n-chunks), 256 threads = 4 waves x 16 q-rows.
__global__ __launch_bounds__(256, 2)
void tok_attn_mfma(const float* __restrict__ qw,            // [b,h,512,64] f32 pre-scaled
                   const __hip_bfloat16* __restrict__ kw,   // [b,h,32,256,64]
                   const __hip_bfloat16* __restrict__ vw,   // [b,h,32,256,64]
                   const float* __restrict__ attn_s,        // [b,h,512,32]
                   float* __restrict__ part0,
                   float* __restrict__ part1)
{
  __shared__ unsigned short kvbuf[18432];    // K as [256][72]  OR  Vt as [64][264]
  __shared__ unsigned short pbuf[64 * 264];  // P as [64 q-rows][256 t + 8 pad]
  const int bh = blockIdx.y, b = bh >> 3, h = bh & 7;
  const int tid = threadIdx.x;
  const int wv = tid >> 6, lane = tid & 63, lg = lane >> 4, lr = lane & 15;
  const int qbase = blockIdx.x * 64 + wv * 16;
  const int n0 = blockIdx.z * 16;

  short8 qfrag[2];
  {
    const float* qrow = qw + ((size_t)bh * 512 + qbase + lr) * 64;
    #pragma unroll
    for (int ks = 0; ks < 2; ks++) {
      float4 u0 = *(const float4*)&qrow[ks * 32 + lg * 8];
      float4 u1 = *(const float4*)&qrow[ks * 32 + lg * 8 + 4];
      short8 t;
      t[0] = f2b(u0.x); t[1] = f2b(u0.y); t[2] = f2b(u0.z); t[3] = f2b(u0.w);
      t[4] = f2b(u1.x); t[5] = f2b(u1.y); t[6] = f2b(u1.z); t[7] = f2b(u1.w);
      qfrag[ks] = t;
    }
  }
  float asv[16];
  {
    const float* ap = attn_s + ((size_t)bh * 512 + qbase + lr) * 32 + n0;
    #pragma unroll
    for (int i = 0; i < 4; i++) {
      float4 u = *(const float4*)&ap[i * 4];
      asv[i * 4 + 0] = u.x; asv[i * 4 + 1] = u.y;
      asv[i * 4 + 2] = u.z; asv[i * 4 + 3] = u.w;
    }
  }

  f32x4 acc[4];
  #pragma unroll
  for (int dt = 0; dt < 4; dt++) acc[dt] = (f32x4){0.f, 0.f, 0.f, 0.f};

  const unsigned short* kwb = (const unsigned short*)(kw + (size_t)bh * 32 * 256 * 64);
  const unsigned short* vwb = (const unsigned short*)(vw + (size_t)bh * 32 * 256 * 64);
  const unsigned int pbase = (wv * 16 + lr) * 264;

  for (int ni = 0; ni < 16; ni++) {
    const int n = n0 + ni;
    __syncthreads();
    {
      const unsigned short* src = kwb + ((size_t)n * 256 + tid) * 64;
      uint4 r[8];
      #pragma unroll
      for (int j = 0; j < 8; j++) r[j] = *(const uint4*)&src[j * 8];
      #pragma unroll
      for (int j = 0; j < 8; j++) *(uint4*)&kvbuf[tid * 72 + j * 8] = r[j];
    }
    __syncthreads();

    f32x4 sfr[16];
    #pragma unroll
    for (int tt = 0; tt < 16; tt++) sfr[tt] = (f32x4){0.f, 0.f, 0.f, 0.f};
    #pragma unroll
    for (int tt = 0; tt < 16; tt++) {
      #pragma unroll
      for (int ks = 0; ks < 2; ks++) {
        short8 kf = *(const short8*)&kvbuf[(16 * tt + lr) * 72 + ks * 32 + lg * 8];
        sfr[tt] = __builtin_amdgcn_mfma_f32_16x16x32_bf16(kf, qfrag[ks], sfr[tt], 0, 0, 0);
      }
    }
    float lsum = 0.f;
    #pragma unroll
    for (int tt = 0; tt < 16; tt++) {
      #pragma unroll
      for (int i = 0; i < 4; i++) {
        float e = __expf(sfr[tt][i]);
        sfr[tt][i] = e;
        lsum += e;
      }
    }
    lsum += __shfl_xor(lsum, 16);
    lsum += __shfl_xor(lsum, 32);
    const float coef = asv[ni] / lsum;
    #pragma unroll
    for (int tt = 0; tt < 16; tt++) {
      uint2 pk;
      pk.x = (unsigned)f2b(sfr[tt][0] * coef) | ((unsigned)f2b(sfr[tt][1] * coef) << 16);
      pk.y = (unsigned)f2b(sfr[tt][2] * coef) | ((unsigned)f2b(sfr[tt][3] * coef) << 16);
      *(uint2*)&pbuf[pbase + tt * 16 + lg * 4] = pk;
    }
    __syncthreads();
    {
      const unsigned short* src = vwb + ((size_t)n * 256 + tid) * 64;
      uint4 r[8];
      #pragma unroll
      for (int j = 0; j < 8; j++) r[j] = *(const uint4*)&src[j * 8];
      const unsigned short* rs = (const unsigned short*)r;
      #pragma unroll
      for (int d = 0; d < 64; d++) kvbuf[d * 264 + tid] = rs[d];
    }
    __syncthreads();

    #pragma unroll
    for (int ks = 0; ks < 8; ks++) {
      short8 pa = *(const short8*)&pbuf[pbase + ks * 32 + lg * 8];
      #pragma unroll
      for (int dt = 0; dt < 4; dt++) {
        short8 vb = *(const short8*)&kvbuf[(16 * dt + lr) * 264 + ks * 32 + lg * 8];
        acc[dt] = __builtin_amdgcn_mfma_f32_16x16x32_bf16(pa, vb, acc[dt], 0, 0, 0);
      }
    }
  }

  float* pout = blockIdx.z ? part1 : part0;
  #pragma unroll
  for (int dt = 0; dt < 4; dt++) {
    #pragma unroll
    for (int i = 0; i < 4; i++) {
      int qg = blockIdx.x * 64 + wv * 16 + lg * 4 + i;
      pout[((size_t)b * 512 + qg) * 512 + h * 64 + dt * 16 + lr] = acc[dt][i];
    }
  }
}

extern "C" void kernel_launch(void* const* d_in, const int* in_sizes, int n_in,
                              void* d_out, int out_size, void* d_ws, size_t ws_size,
                              hipStream_t stream)
{
  (void)in_sizes; (void)n_in; (void)out_size; (void)ws_size;
  const float* q    = (const float*)d_in[0];
  const float* k_w  = (const float*)d_in[1];
  const float* v_w  = (const float*)d_in[2];
  const float* k_s  = (const float*)d_in[3];
  const float* v_s  = (const float*)d_in[4];
  const float* W_qs = (const float*)d_in[5];  const float* b_qs = (const float*)d_in[6];
  const float* W_ks = (const float*)d_in[7];  const float* b_ks = (const float*)d_in[8];
  const float* W_vs = (const float*)d_in[9];  const float* b_vs = (const float*)d_in[10];
  const float* W_qw = (const float*)d_in[11]; const float* b_qw = (const float*)d_in[12];
  const float* W_kw = (const float*)d_in[13]; const float* b_kw = (const float*)d_in[14];
  const float* W_vw = (const float*)d_in[15]; const float* b_vw = (const float*)d_in[16];
  const float* W_fc1= (const float*)d_in[17]; const float* b_fc1= (const float*)d_in[18];
  const float* W_fc = (const float*)d_in[19]; const float* b_fc = (const float*)d_in[20];
  float* out = (float*)d_out;

  char* ws = (char*)d_ws;
  const size_t MB = 1ull << 20;
  const size_t KB = 1ull << 10;
  float* qs_ws    = (float*)(ws + 0 * MB);       // [b,h,512,64] 4 MB (dead after sent_attn)
  float* qw_ws    = (float*)(ws + 4 * MB);       // [b,h,512,64] 4 MB
  float* ks_ws    = (float*)(ws + 8 * MB);       // [b,h,32,64] 256 KB
  unsigned short* WkT = (unsigned short*)(ws + 8 * MB + 512 * KB);  // [512n][512k] bf16, 512 KB
  float* vs_ws    = (float*)(ws + 9 * MB);       // [b,h,32,64] 256 KB
  unsigned short* WvT = (unsigned short*)(ws + 9 * MB + 512 * KB);  // 512 KB
  float* attns_ws = (float*)(ws + 10 * MB);      // [b,h,512,32] 2 MB
  float* ctxs_ws  = (float*)(ws + 12 * MB);      // [b,512,512] 4 MB (dead after fc1 gemm)
  float* ctxsf_ws = (float*)(ws + 16 * MB);      // [b,512,512] 4 MB
  __hip_bfloat16* kw_ws = (__hip_bfloat16*)(ws + 24 * MB);  // [b,h,32,256,64] 32 MB
  __hip_bfloat16* vw_ws = (__hip_bfloat16*)(ws + 56 * MB);  // [b,h,32,256,64] 32 MB
  float* part0 = (float*)(ws + 0 * MB);          // over qs_ws   (4 MB)
  float* part1 = (float*)(ws + 12 * MB);         // over ctxs_ws (4 MB)

  dim3 blk(256);
  // weight transpose-casts for the MFMA projections
  wcast_t<<<dim3(8, 8, 2), blk, 0, stream>>>(W_kw, WkT, W_vw, WvT);
  // small projections (MFMA, bf16x3 split): qs+qw fused, ks+vs fused
  sgemm_mfma<2><<<dim3(32, 8, 2), blk, 0, stream>>>(
      q, q, nullptr, nullptr, W_qs, W_qw, b_qs, b_qw, qs_ws, qw_ws, SCALE_F, 2048, 512);
  sgemm_mfma<3><<<dim3(2, 8, 2), blk, 0, stream>>>(
      k_s, v_s, nullptr, nullptr, W_ks, W_vs, b_ks, b_vs, ks_ws, vs_ws, 1.f, 128, 512);
  // big projections (MFMA path)
  proj_gemm<<<dim3(256, 4), blk, 0, stream>>>(k_w, WkT, b_kw, kw_ws);
  proj_gemm<<<dim3(256, 4), blk, 0, stream>>>(v_w, WvT, b_vw, vw_ws);
  // sentence attention (+ attn_s for token level)
  sent_attn<<<dim3(16, 32), blk, 0, stream>>>(qs_ws, ks_ws, vs_ws, attns_ws, ctxs_ws);
  // ctx_s @ W_fc1
  sgemm_mfma<0><<<dim3(32, 8, 1), blk, 0, stream>>>(
      ctxs_ws, ctxs_ws, nullptr, nullptr, W_fc1, W_fc1, b_fc1, b_fc1,
      ctxsf_ws, ctxsf_ws, 1.f, 2048, 512);
  // token attention (MFMA) -> partials (summed in final GEMM staging)
  tok_attn_mfma<<<dim3(8, 32, 2), blk, 0, stream>>>(qw_ws, kw_ws, vw_ws, attns_ws, part0, part1);
  // final combine: concat([ctx_s_fc1, part0+part1]) @ W_fc + b_fc
  sgemm_mfma<1><<<dim3(32, 8, 1), blk, 0, stream>>>(
      ctxsf_ws, ctxsf_ws, part0, part1, W_fc, W_fc, b_fc, b_fc,
      out, out, 1.f, 2048, 1024);
}